// Round 1
// baseline (369.525 us; speedup 1.0000x reference)
//
#include <hip/hip_runtime.h>
#include <math.h>

#define N_ROWS 32768
#define K_CODES 4096
#define DIM 64
#define SPLITS 8
#define CODES_PER_SPLIT (K_CODES / SPLITS)   // 512
#define ROWS_PER_BLOCK 256

// ---------------------------------------------------------------------------
// Kernel 0: per-code squared norm  sq[k] = sum_j embed[k][j]^2
// ---------------------------------------------------------------------------
__global__ void embed_sq_kernel(const float* __restrict__ embed,
                                float* __restrict__ sq) {
    int k = blockIdx.x * blockDim.x + threadIdx.x;
    if (k >= K_CODES) return;
    const float4* e4 = reinterpret_cast<const float4*>(embed + (size_t)k * DIM);
    float a0 = 0.f, a1 = 0.f, a2 = 0.f, a3 = 0.f;
#pragma unroll
    for (int i = 0; i < DIM / 4; ++i) {
        float4 v = e4[i];
        a0 = fmaf(v.x, v.x, a0);
        a1 = fmaf(v.y, v.y, a1);
        a2 = fmaf(v.z, v.z, a2);
        a3 = fmaf(v.w, v.w, a3);
    }
    sq[k] = (a0 + a1) + (a2 + a3);
}

// ---------------------------------------------------------------------------
// Kernel 1: fused dist + argmax over a K-split.
// One thread per row; row held in 64 VGPRs; codebook reads are wave-uniform
// (k uniform) -> scalar loads feeding v_fmac with SGPR operand.
// grid = (N_ROWS/ROWS_PER_BLOCK, SPLITS), block = 256.
// ---------------------------------------------------------------------------
__global__ __launch_bounds__(256, 4) void dist_argmax_kernel(
    const float* __restrict__ x, const float* __restrict__ embed,
    const float* __restrict__ sq, float* __restrict__ pbest,
    int* __restrict__ pidx) {
    const int row = blockIdx.x * ROWS_PER_BLOCK + threadIdx.x;
    const int split = blockIdx.y;
    const int k0 = split * CODES_PER_SPLIT;

    // Load this thread's row into registers.
    float xr[DIM];
    const float4* x4 = reinterpret_cast<const float4*>(x + (size_t)row * DIM);
#pragma unroll
    for (int i = 0; i < DIM / 4; ++i) {
        float4 v = x4[i];
        xr[4 * i + 0] = v.x;
        xr[4 * i + 1] = v.y;
        xr[4 * i + 2] = v.z;
        xr[4 * i + 3] = v.w;
    }

    float best = -INFINITY;
    int bi = k0;
    for (int k = k0; k < k0 + CODES_PER_SPLIT; ++k) {
        const float4* e4 =
            reinterpret_cast<const float4*>(embed + (size_t)k * DIM);
        float a0 = 0.f, a1 = 0.f, a2 = 0.f, a3 = 0.f;
#pragma unroll
        for (int i = 0; i < DIM / 4; ++i) {
            float4 e = e4[i];
            a0 = fmaf(xr[4 * i + 0], e.x, a0);
            a1 = fmaf(xr[4 * i + 1], e.y, a1);
            a2 = fmaf(xr[4 * i + 2], e.z, a2);
            a3 = fmaf(xr[4 * i + 3], e.w, a3);
        }
        // dist = 2*dot - ||e||^2 ; 2*dot is exact, fmaf matches reference.
        float dist = fmaf(2.0f, (a0 + a1) + (a2 + a3), -sq[k]);
        if (dist > best) {  // strict > keeps first occurrence (jnp.argmax)
            best = dist;
            bi = k;
        }
    }
    pbest[(size_t)split * N_ROWS + row] = best;
    pidx[(size_t)split * N_ROWS + row] = bi;
}

// ---------------------------------------------------------------------------
// Kernel 2: combine splits, gather quantize rows, write index-as-float.
// One thread per (row, float4-chunk): t in [0, N_ROWS*16).
// ---------------------------------------------------------------------------
__global__ void combine_kernel(const float* __restrict__ pbest,
                               const int* __restrict__ pidx,
                               const float* __restrict__ embed,
                               float* __restrict__ out) {
    const int t = blockIdx.x * blockDim.x + threadIdx.x;
    const int row = t >> 4;
    const int q = t & 15;
    if (row >= N_ROWS) return;

    float best = -INFINITY;
    int bi = 0;
#pragma unroll
    for (int s = 0; s < SPLITS; ++s) {
        float b = pbest[(size_t)s * N_ROWS + row];
        int i = pidx[(size_t)s * N_ROWS + row];
        if (b > best) {  // splits are ascending in k; strict > keeps earliest
            best = b;
            bi = i;
        }
    }

    const float4* e4 = reinterpret_cast<const float4*>(embed);
    float4 v = e4[(size_t)bi * (DIM / 4) + q];
    reinterpret_cast<float4*>(out)[(size_t)row * (DIM / 4) + q] = v;
    if (q == 0) {
        out[(size_t)N_ROWS * DIM + row] = (float)bi;  // index as float
    }
}

// ---------------------------------------------------------------------------
extern "C" void kernel_launch(void* const* d_in, const int* in_sizes, int n_in,
                              void* d_out, int out_size, void* d_ws,
                              size_t ws_size, hipStream_t stream) {
    const float* x = (const float*)d_in[0];
    const float* embed = (const float*)d_in[1];
    float* out = (float*)d_out;

    // Workspace carving: sq (16 KB) | pbest (1 MB) | pidx (1 MB)
    char* ws = (char*)d_ws;
    float* sq = (float*)ws;
    float* pbest = (float*)(ws + 16384);
    int* pidx = (int*)(ws + 16384 + sizeof(float) * SPLITS * N_ROWS);

    embed_sq_kernel<<<(K_CODES + 255) / 256, 256, 0, stream>>>(embed, sq);

    dim3 grid(N_ROWS / ROWS_PER_BLOCK, SPLITS);
    dist_argmax_kernel<<<grid, 256, 0, stream>>>(x, embed, sq, pbest, pidx);

    const int combine_threads = N_ROWS * (DIM / 4);
    combine_kernel<<<(combine_threads + 255) / 256, 256, 0, stream>>>(
        pbest, pidx, embed, out);
}

// Round 2
// 208.780 us; speedup vs baseline: 1.7699x; 1.7699x over previous
//
#include <hip/hip_runtime.h>
#include <math.h>

#define N_ROWS 32768
#define K_CODES 4096
#define DIM 64
#define COL_TILES (K_CODES / 16)   // 256
#define QUANT_ELEMS (N_ROWS * DIM) // 2097152

typedef _Float16 half8 __attribute__((ext_vector_type(8)));
typedef float floatx4 __attribute__((ext_vector_type(4)));

// ---------------------------------------------------------------------------
// Kernel 0: per-code squared norm  sq[k] = sum_j embed[k][j]^2
// ---------------------------------------------------------------------------
__global__ void embed_sq_kernel(const float* __restrict__ embed,
                                float* __restrict__ sq) {
    int k = blockIdx.x * blockDim.x + threadIdx.x;
    if (k >= K_CODES) return;
    const float4* e4 = reinterpret_cast<const float4*>(embed + (size_t)k * DIM);
    float a0 = 0.f, a1 = 0.f, a2 = 0.f, a3 = 0.f;
#pragma unroll
    for (int i = 0; i < DIM / 4; ++i) {
        float4 v = e4[i];
        a0 = fmaf(v.x, v.x, a0);
        a1 = fmaf(v.y, v.y, a1);
        a2 = fmaf(v.z, v.z, a2);
        a3 = fmaf(v.w, v.w, a3);
    }
    sq[k] = (a0 + a1) + (a2 + a3);
}

// ---------------------------------------------------------------------------
// Kernel 1: convert embed -> fp16 hi/lo B-fragments in MFMA fragment order.
// For col-tile c (16 codes), kstep s (k = 32*s..32*s+31), lane l holds
// B[k=(l>>4)*8+j + 32*s][n = l&15] = embed[c*16 + (l&15)][(l>>4)*8+j+32*s].
// Stored so the main kernel's lane l reads 16 B at ((c*2+s)*64 + l)*16.
// 32768 threads total.
// ---------------------------------------------------------------------------
__global__ void frag_convert_kernel(const float* __restrict__ embed,
                                    half8* __restrict__ ehi,
                                    half8* __restrict__ elo) {
    int t = blockIdx.x * blockDim.x + threadIdx.x;
    if (t >= COL_TILES * 2 * 64) return;
    int l = t & 63;
    int s = (t >> 6) & 1;
    int c = t >> 7;
    int code = c * 16 + (l & 15);
    int koff = (l >> 4) * 8 + 32 * s;
    const float* src = embed + (size_t)code * DIM + koff;
    half8 h, lo;
#pragma unroll
    for (int j = 0; j < 8; ++j) {
        float v = src[j];
        _Float16 hi = (_Float16)v;
        h[j] = hi;
        lo[j] = (_Float16)(v - (float)hi);
    }
    size_t dst = (size_t)(c * 2 + s) * 64 + l;
    ehi[dst] = h;
    elo[dst] = lo;
}

// ---------------------------------------------------------------------------
// Kernel 2: fused dist(GEMM) + argmax + gather + write.
// Block = 256 threads = 4 waves; each wave owns 16 rows, sweeps all 4096
// codes. dist = dot(2x, e) - ||e||^2 ; -||e||^2 is the accumulator init,
// 2x is folded into the A fragment (exact).
// fp16x2 split, 3 terms: xh*eh + xl*eh + xh*el  (error ~1e-5 absolute).
// ---------------------------------------------------------------------------
__global__ __launch_bounds__(256) void fused_dist_argmax_kernel(
    const float* __restrict__ x, const float* __restrict__ embed,
    const float* __restrict__ sq, const half8* __restrict__ ehi,
    const half8* __restrict__ elo, float* __restrict__ out) {
    const int lane = threadIdx.x & 63;
    const int wave = threadIdx.x >> 6;
    const int row_base = blockIdx.x * 64 + wave * 16;
    const int m = lane & 15;    // A row within tile; also C col (code)
    const int quad = lane >> 4;

    // Persistent A fragments for this wave's 16 rows (scaled by 2).
    // A[m = lane&15][k = quad*8 + j + 32*s]
    half8 ah[2], al[2];
    {
        const int arow = row_base + m;
#pragma unroll
        for (int s = 0; s < 2; ++s) {
            const float* src = x + (size_t)arow * DIM + quad * 8 + 32 * s;
            half8 h, lo;
#pragma unroll
            for (int j = 0; j < 8; ++j) {
                float v = 2.0f * src[j];
                _Float16 hi = (_Float16)v;
                h[j] = hi;
                lo[j] = (_Float16)(v - (float)hi);
            }
            ah[s] = h;
            al[s] = lo;
        }
    }

    float best[4] = {-INFINITY, -INFINITY, -INFINITY, -INFINITY};
    int idx[4] = {0, 0, 0, 0};

    for (int c = 0; c < COL_TILES; ++c) {
        const int colbase = c * 16 + m;
        const float nsq = -sq[colbase];
        floatx4 acc = {nsq, nsq, nsq, nsq};
        const size_t fb = (size_t)(c * 2) * 64 + lane;
        half8 bh0 = ehi[fb];
        half8 bh1 = ehi[fb + 64];
        half8 bl0 = elo[fb];
        half8 bl1 = elo[fb + 64];
        acc = __builtin_amdgcn_mfma_f32_16x16x32_f16(ah[0], bh0, acc, 0, 0, 0);
        acc = __builtin_amdgcn_mfma_f32_16x16x32_f16(ah[1], bh1, acc, 0, 0, 0);
        acc = __builtin_amdgcn_mfma_f32_16x16x32_f16(al[0], bh0, acc, 0, 0, 0);
        acc = __builtin_amdgcn_mfma_f32_16x16x32_f16(al[1], bh1, acc, 0, 0, 0);
        acc = __builtin_amdgcn_mfma_f32_16x16x32_f16(ah[0], bl0, acc, 0, 0, 0);
        acc = __builtin_amdgcn_mfma_f32_16x16x32_f16(ah[1], bl1, acc, 0, 0, 0);
#pragma unroll
        for (int r = 0; r < 4; ++r) {
            if (acc[r] > best[r]) {  // strict >: earliest tile wins ties
                best[r] = acc[r];
                idx[r] = colbase;
            }
        }
    }

    // C/D layout: col = lane&15 (=m), row = quad*4 + reg.
    // Reduce (best, idx) across the 16 lanes sharing each row group;
    // butterfly leaves the result in ALL 16 lanes.
#pragma unroll
    for (int r = 0; r < 4; ++r) {
        float bv = best[r];
        int bi = idx[r];
#pragma unroll
        for (int d = 1; d < 16; d <<= 1) {
            float ov = __shfl_xor(bv, d);
            int oi = __shfl_xor(bi, d);
            if (ov > bv || (ov == bv && oi < bi)) {  // smaller index on tie
                bv = ov;
                bi = oi;
            }
        }
        const int row = row_base + quad * 4 + r;
        // 16 lanes cooperatively write the 64-float quantize row (coalesced).
        const float4* e4 = reinterpret_cast<const float4*>(embed);
        reinterpret_cast<float4*>(out)[(size_t)row * (DIM / 4) + m] =
            e4[(size_t)bi * (DIM / 4) + m];
        if (m == 0) out[(size_t)QUANT_ELEMS + row] = (float)bi;
    }
}

// ---------------------------------------------------------------------------
extern "C" void kernel_launch(void* const* d_in, const int* in_sizes, int n_in,
                              void* d_out, int out_size, void* d_ws,
                              size_t ws_size, hipStream_t stream) {
    const float* x = (const float*)d_in[0];
    const float* embed = (const float*)d_in[1];
    float* out = (float*)d_out;

    // ws: sq (16 KB) | ehi (512 KB) | elo (512 KB)  — ~1.04 MB total
    char* ws = (char*)d_ws;
    float* sq = (float*)ws;
    half8* ehi = (half8*)(ws + 16384);
    half8* elo = (half8*)(ws + 16384 + 524288);

    embed_sq_kernel<<<(K_CODES + 255) / 256, 256, 0, stream>>>(embed, sq);

    frag_convert_kernel<<<(COL_TILES * 2 * 64 + 255) / 256, 256, 0, stream>>>(
        embed, ehi, elo);

    fused_dist_argmax_kernel<<<N_ROWS / 64, 256, 0, stream>>>(x, embed, sq,
                                                              ehi, elo, out);
}

// Round 3
// 144.502 us; speedup vs baseline: 2.5572x; 1.4448x over previous
//
#include <hip/hip_runtime.h>
#include <math.h>

#define N_ROWS 32768
#define K_CODES 4096
#define DIM 64
#define SPLITS 2
#define TILES_TOTAL (K_CODES / 32)              // 128
#define TILES_PER_SPLIT (TILES_TOTAL / SPLITS)  // 64
#define QUANT_ELEMS (N_ROWS * DIM)              // 2097152

typedef _Float16 half8 __attribute__((ext_vector_type(8)));
typedef float floatx16 __attribute__((ext_vector_type(16)));

// ---------------------------------------------------------------------------
// Kernel 0: per-code squared norm  sq[k] = sum_j embed[k][j]^2
// ---------------------------------------------------------------------------
__global__ void embed_sq_kernel(const float* __restrict__ embed,
                                float* __restrict__ sq) {
    int k = blockIdx.x * blockDim.x + threadIdx.x;
    if (k >= K_CODES) return;
    const float4* e4 = reinterpret_cast<const float4*>(embed + (size_t)k * DIM);
    float a0 = 0.f, a1 = 0.f, a2 = 0.f, a3 = 0.f;
#pragma unroll
    for (int i = 0; i < DIM / 4; ++i) {
        float4 v = e4[i];
        a0 = fmaf(v.x, v.x, a0);
        a1 = fmaf(v.y, v.y, a1);
        a2 = fmaf(v.z, v.z, a2);
        a3 = fmaf(v.w, v.w, a3);
    }
    sq[k] = (a0 + a1) + (a2 + a3);
}

// ---------------------------------------------------------------------------
// Kernel 1: embed -> fp16 hi/lo B-fragments for mfma_f32_32x32x16_f16.
// Tile c = 32 codes; kstep s covers k=16s..16s+15. Lane l holds
// B[k=(l>>5)*8+j+16s][col=l&31] = embed[c*32+(l&31)][(l>>5)*8+j+16s].
// dst element index = (c*4+s)*64 + l == t.  32768 threads.
// ---------------------------------------------------------------------------
__global__ void frag_convert_kernel(const float* __restrict__ embed,
                                    half8* __restrict__ ehi,
                                    half8* __restrict__ elo) {
    int t = blockIdx.x * blockDim.x + threadIdx.x;
    if (t >= TILES_TOTAL * 4 * 64) return;
    int l = t & 63;
    int s = (t >> 6) & 3;
    int c = t >> 8;
    int code = c * 32 + (l & 31);
    int koff = (l >> 5) * 8 + 16 * s;
    const float* src = embed + (size_t)code * DIM + koff;
    half8 h, lo;
#pragma unroll
    for (int j = 0; j < 8; ++j) {
        float v = src[j];
        _Float16 hi = (_Float16)v;
        h[j] = hi;
        lo[j] = (_Float16)(v - (float)hi);
    }
    ehi[t] = h;
    elo[t] = lo;
}

// ---------------------------------------------------------------------------
// Kernel 2: fused dist(GEMM 32x32x16) + per-split argmax.
// Wave owns 32 rows; sweeps TILES_PER_SPLIT 32-code tiles.
// dist = dot(2x, e) - ||e||^2 ; -||e||^2 is the accumulator init, 2x folded
// into A (exact). fp16 split, 3 terms: xh*eh + xl*eh + xh*el.
// grid = (256, SPLITS), block = 256 (4 waves = 128 rows).
// ---------------------------------------------------------------------------
__global__ __launch_bounds__(256, 2) void fused_dist_argmax32(
    const float* __restrict__ x, const float* __restrict__ sq,
    const half8* __restrict__ ehi, const half8* __restrict__ elo,
    float* __restrict__ pbest, int* __restrict__ pidx) {
    const int lane = threadIdx.x & 63;
    const int wave = threadIdx.x >> 6;
    const int col = lane & 31;    // B col (code within tile); A row
    const int half_ = lane >> 5;  // k-half
    const int row_base = blockIdx.x * 128 + wave * 32;
    const int split = blockIdx.y;
    const int c0 = split * TILES_PER_SPLIT;

    // Persistent A fragments (scaled by 2): A[m=col][k=half_*8+j+16s]
    half8 ah[4], al[4];
    {
        const float* xs = x + (size_t)(row_base + col) * DIM + half_ * 8;
#pragma unroll
        for (int s = 0; s < 4; ++s) {
            half8 h, lo;
#pragma unroll
            for (int j = 0; j < 8; ++j) {
                float v = 2.0f * xs[16 * s + j];
                _Float16 hi = (_Float16)v;
                h[j] = hi;
                lo[j] = (_Float16)(v - (float)hi);
            }
            ah[s] = h;
            al[s] = lo;
        }
    }

    float best[16];
    int bidx[16];
#pragma unroll
    for (int r = 0; r < 16; ++r) {
        best[r] = -INFINITY;
        bidx[r] = 0;
    }

    const half8* ph = ehi + (size_t)c0 * 256 + lane;
    const half8* pl = elo + (size_t)c0 * 256 + lane;
    const float* psq = sq + c0 * 32 + col;

    for (int c = 0; c < TILES_PER_SPLIT; ++c) {
        half8 bh0 = ph[0], bh1 = ph[64], bh2 = ph[128], bh3 = ph[192];
        half8 bl0 = pl[0], bl1 = pl[64], bl2 = pl[128], bl3 = pl[192];
        float nsq = -psq[0];
        ph += 256;
        pl += 256;
        psq += 32;

        floatx16 acc;
#pragma unroll
        for (int r = 0; r < 16; ++r) acc[r] = nsq;
        acc = __builtin_amdgcn_mfma_f32_32x32x16_f16(ah[0], bh0, acc, 0, 0, 0);
        acc = __builtin_amdgcn_mfma_f32_32x32x16_f16(ah[1], bh1, acc, 0, 0, 0);
        acc = __builtin_amdgcn_mfma_f32_32x32x16_f16(ah[2], bh2, acc, 0, 0, 0);
        acc = __builtin_amdgcn_mfma_f32_32x32x16_f16(ah[3], bh3, acc, 0, 0, 0);
        acc = __builtin_amdgcn_mfma_f32_32x32x16_f16(al[0], bh0, acc, 0, 0, 0);
        acc = __builtin_amdgcn_mfma_f32_32x32x16_f16(al[1], bh1, acc, 0, 0, 0);
        acc = __builtin_amdgcn_mfma_f32_32x32x16_f16(al[2], bh2, acc, 0, 0, 0);
        acc = __builtin_amdgcn_mfma_f32_32x32x16_f16(al[3], bh3, acc, 0, 0, 0);
        acc = __builtin_amdgcn_mfma_f32_32x32x16_f16(ah[0], bl0, acc, 0, 0, 0);
        acc = __builtin_amdgcn_mfma_f32_32x32x16_f16(ah[1], bl1, acc, 0, 0, 0);
        acc = __builtin_amdgcn_mfma_f32_32x32x16_f16(ah[2], bl2, acc, 0, 0, 0);
        acc = __builtin_amdgcn_mfma_f32_32x32x16_f16(ah[3], bl3, acc, 0, 0, 0);

        const int cidx = (c0 + c) * 32 + col;
#pragma unroll
        for (int r = 0; r < 16; ++r) {
            if (acc[r] > best[r]) {  // strict >: earliest tile wins ties
                best[r] = acc[r];
                bidx[r] = cidx;
            }
        }
    }

    // C/D layout (32x32): col = lane&31, row = (r&3) + 8*(r>>2) + 4*half_.
    // Reduce across the 32 lanes of each half (same rows, different cols).
#pragma unroll
    for (int r = 0; r < 16; ++r) {
        float bv = best[r];
        int bi = bidx[r];
#pragma unroll
        for (int d = 1; d < 32; d <<= 1) {
            float ov = __shfl_xor(bv, d);
            int oi = __shfl_xor(bi, d);
            if (ov > bv || (ov == bv && oi < bi)) {  // smaller idx on tie
                bv = ov;
                bi = oi;
            }
        }
        if (col == 0) {
            const int row = row_base + (r & 3) + 8 * (r >> 2) + 4 * half_;
            pbest[(size_t)split * N_ROWS + row] = bv;
            pidx[(size_t)split * N_ROWS + row] = bi;
        }
    }
}

// ---------------------------------------------------------------------------
// Kernel 3: combine splits, gather quantize rows, write index-as-float.
// One thread per (row, float4-chunk): t in [0, N_ROWS*16).
// ---------------------------------------------------------------------------
__global__ void combine_kernel(const float* __restrict__ pbest,
                               const int* __restrict__ pidx,
                               const float* __restrict__ embed,
                               float* __restrict__ out) {
    const int t = blockIdx.x * blockDim.x + threadIdx.x;
    const int row = t >> 4;
    const int q = t & 15;
    if (row >= N_ROWS) return;

    float best = -INFINITY;
    int bi = 0;
#pragma unroll
    for (int s = 0; s < SPLITS; ++s) {
        float b = pbest[(size_t)s * N_ROWS + row];
        int i = pidx[(size_t)s * N_ROWS + row];
        if (b > best) {  // splits ascending in k; strict > keeps earliest
            best = b;
            bi = i;
        }
    }

    const float4* e4 = reinterpret_cast<const float4*>(embed);
    float4 v = e4[(size_t)bi * (DIM / 4) + q];
    reinterpret_cast<float4*>(out)[(size_t)row * (DIM / 4) + q] = v;
    if (q == 0) {
        out[(size_t)QUANT_ELEMS + row] = (float)bi;  // index as float
    }
}

// ---------------------------------------------------------------------------
extern "C" void kernel_launch(void* const* d_in, const int* in_sizes, int n_in,
                              void* d_out, int out_size, void* d_ws,
                              size_t ws_size, hipStream_t stream) {
    const float* x = (const float*)d_in[0];
    const float* embed = (const float*)d_in[1];
    float* out = (float*)d_out;

    // ws: sq 16KB | ehi 512KB | elo 512KB | pbest 256KB | pidx 256KB
    char* ws = (char*)d_ws;
    float* sq = (float*)ws;
    half8* ehi = (half8*)(ws + 16384);
    half8* elo = (half8*)(ws + 16384 + 524288);
    float* pbest = (float*)(ws + 16384 + 2 * 524288);
    int* pidx = (int*)(ws + 16384 + 2 * 524288 + SPLITS * N_ROWS * 4);

    embed_sq_kernel<<<(K_CODES + 255) / 256, 256, 0, stream>>>(embed, sq);

    frag_convert_kernel<<<(TILES_TOTAL * 4 * 64 + 255) / 256, 256, 0,
                          stream>>>(embed, ehi, elo);

    dim3 grid(N_ROWS / 128, SPLITS);
    fused_dist_argmax32<<<grid, 256, 0, stream>>>(x, sq, ehi, elo, pbest,
                                                  pidx);

    const int combine_threads = N_ROWS * (DIM / 4);
    combine_kernel<<<(combine_threads + 255) / 256, 256, 0, stream>>>(
        pbest, pidx, embed, out);
}

// Round 4
// 122.623 us; speedup vs baseline: 3.0135x; 1.1784x over previous
//
#include <hip/hip_runtime.h>
#include <math.h>

#define N_ROWS 32768
#define K_CODES 4096
#define DIM 64
#define SPLITS 4
#define TILES_TOTAL (K_CODES / 32)              // 128
#define TILES_PER_SPLIT (TILES_TOTAL / SPLITS)  // 32
#define QUANT_ELEMS (N_ROWS * DIM)              // 2097152

typedef _Float16 half8 __attribute__((ext_vector_type(8)));
typedef float floatx16 __attribute__((ext_vector_type(16)));

// async global->LDS, 16 B per lane (wave-uniform base + lane*16 layout)
__device__ __forceinline__ void gld16(const void* g, void* l) {
    __builtin_amdgcn_global_load_lds(
        (const __attribute__((address_space(1))) unsigned int*)g,
        (__attribute__((address_space(3))) unsigned int*)l, 16, 0, 0);
}

// ---------------------------------------------------------------------------
// Kernel 0 (fused): embed -> fp16 hi/lo B-fragments for mfma_f32_32x32x16_f16
// AND per-code squared norms (LDS reduction).
// Tile c = 32 codes; kstep s covers k=16s..16s+15. Thread t = c*256 + s*64 + l
// holds B[k=(l>>5)*8+j+16s][col=l&31] = embed[c*32+(l&31)][(l>>5)*8+j+16s].
// One 256-thread block per tile (grid = 128 blocks).
// ---------------------------------------------------------------------------
__global__ void prep_kernel(const float* __restrict__ embed,
                            float* __restrict__ sq, half8* __restrict__ ehi,
                            half8* __restrict__ elo) {
    __shared__ float part[256];
    const int tid = threadIdx.x;
    const int t = blockIdx.x * 256 + tid;
    const int l = t & 63;
    const int s = (t >> 6) & 3;
    const int c = blockIdx.x;  // == t >> 8
    const int col = l & 31;
    const int code = c * 32 + col;
    const int koff = (l >> 5) * 8 + 16 * s;
    const float* src = embed + (size_t)code * DIM + koff;
    half8 h, lo;
    float ss = 0.f;
#pragma unroll
    for (int j = 0; j < 8; ++j) {
        float v = src[j];
        ss = fmaf(v, v, ss);
        _Float16 hi = (_Float16)v;
        h[j] = hi;
        lo[j] = (_Float16)(v - (float)hi);
    }
    ehi[t] = h;
    elo[t] = lo;
    part[tid] = ss;
    __syncthreads();
    if (tid < 32) {
        // code (c*32 + tid)'s 8 partials live at tid + 32*h + 64*s
        float a = 0.f;
#pragma unroll
        for (int q = 0; q < 8; ++q) a += part[tid + 32 * (q & 1) + 64 * (q >> 1)];
        sq[c * 32 + tid] = a;
    }
}

// ---------------------------------------------------------------------------
// Kernel 1: fused dist(GEMM 32x32x16) + per-split argmax, LDS-staged B.
// Block = 4 waves x 32 rows = 128 rows; all 4 waves share each 8 KB B tile
// staged via global_load_lds (two-barrier K-loop).
// dist = dot(2x,e) - ||e||^2 ; -||e||^2 = acc init, 2x folded into A (exact).
// fp16 split, 3 terms: xh*eh + xl*eh + xh*el.
// grid = (N_ROWS/128, SPLITS) = (256, 4), block = 256.
// ---------------------------------------------------------------------------
__global__ __launch_bounds__(256, 4) void fused_dist_argmax32(
    const float* __restrict__ x, const float* __restrict__ sq,
    const half8* __restrict__ ehi, const half8* __restrict__ elo,
    float* __restrict__ pbest, int* __restrict__ pidx) {
    __shared__ char lbuf[8192];  // [0,4K) = ehi tile, [4K,8K) = elo tile
    const int tid = threadIdx.x;
    const int lane = tid & 63;
    const int wave = tid >> 6;
    const int col = lane & 31;    // B col (code within tile); A row
    const int half_ = lane >> 5;  // k-half
    const int row_base = blockIdx.x * 128 + wave * 32;
    const int split = blockIdx.y;
    const int c0 = split * TILES_PER_SPLIT;

    // Persistent A fragments (scaled by 2): A[m=col][k=half_*8+j+16s]
    half8 ah[4], al[4];
    {
        const float* xs = x + (size_t)(row_base + col) * DIM + half_ * 8;
#pragma unroll
        for (int s = 0; s < 4; ++s) {
            half8 h, lo;
#pragma unroll
            for (int j = 0; j < 8; ++j) {
                float v = 2.0f * xs[16 * s + j];
                _Float16 hi = (_Float16)v;
                h[j] = hi;
                lo[j] = (_Float16)(v - (float)hi);
            }
            ah[s] = h;
            al[s] = lo;
        }
    }

    float best[16];
    int bidx[16];
#pragma unroll
    for (int r = 0; r < 16; ++r) {
        best[r] = -INFINITY;
        bidx[r] = 0;
    }

    const char* gh = (const char*)(ehi + (size_t)c0 * 256);
    const char* gl = (const char*)(elo + (size_t)c0 * 256);
    const float* psq = sq + c0 * 32 + col;
    const half8* lh = (const half8*)lbuf;
    const half8* ll = (const half8*)(lbuf + 4096);

    for (int c = 0; c < TILES_PER_SPLIT; ++c) {
        // Stage tile c: 256 threads x 2 x 16 B = 8 KB.
        gld16(gh + (size_t)c * 4096 + (size_t)tid * 16, lbuf + tid * 16);
        gld16(gl + (size_t)c * 4096 + (size_t)tid * 16, lbuf + 4096 + tid * 16);
        float nsq = -psq[(size_t)c * 32];
        __syncthreads();  // drains vmcnt(0): LDS tile ready

        floatx16 acc;
#pragma unroll
        for (int r = 0; r < 16; ++r) acc[r] = nsq;
        half8 b;
        b = lh[lane];
        acc = __builtin_amdgcn_mfma_f32_32x32x16_f16(ah[0], b, acc, 0, 0, 0);
        acc = __builtin_amdgcn_mfma_f32_32x32x16_f16(al[0], b, acc, 0, 0, 0);
        b = lh[64 + lane];
        acc = __builtin_amdgcn_mfma_f32_32x32x16_f16(ah[1], b, acc, 0, 0, 0);
        acc = __builtin_amdgcn_mfma_f32_32x32x16_f16(al[1], b, acc, 0, 0, 0);
        b = lh[128 + lane];
        acc = __builtin_amdgcn_mfma_f32_32x32x16_f16(ah[2], b, acc, 0, 0, 0);
        acc = __builtin_amdgcn_mfma_f32_32x32x16_f16(al[2], b, acc, 0, 0, 0);
        b = lh[192 + lane];
        acc = __builtin_amdgcn_mfma_f32_32x32x16_f16(ah[3], b, acc, 0, 0, 0);
        acc = __builtin_amdgcn_mfma_f32_32x32x16_f16(al[3], b, acc, 0, 0, 0);
        b = ll[lane];
        acc = __builtin_amdgcn_mfma_f32_32x32x16_f16(ah[0], b, acc, 0, 0, 0);
        b = ll[64 + lane];
        acc = __builtin_amdgcn_mfma_f32_32x32x16_f16(ah[1], b, acc, 0, 0, 0);
        b = ll[128 + lane];
        acc = __builtin_amdgcn_mfma_f32_32x32x16_f16(ah[2], b, acc, 0, 0, 0);
        b = ll[192 + lane];
        acc = __builtin_amdgcn_mfma_f32_32x32x16_f16(ah[3], b, acc, 0, 0, 0);
        __syncthreads();  // protect LDS buffer before next stage

        const int cidx = (c0 + c) * 32 + col;
#pragma unroll
        for (int r = 0; r < 16; ++r) {
            if (acc[r] > best[r]) {  // strict >: earliest tile wins ties
                best[r] = acc[r];
                bidx[r] = cidx;
            }
        }
    }

    // C/D layout (32x32): col = lane&31, row = (r&3) + 8*(r>>2) + 4*half_.
#pragma unroll
    for (int r = 0; r < 16; ++r) {
        float bv = best[r];
        int bi = bidx[r];
#pragma unroll
        for (int d = 1; d < 32; d <<= 1) {
            float ov = __shfl_xor(bv, d);
            int oi = __shfl_xor(bi, d);
            if (ov > bv || (ov == bv && oi < bi)) {  // smaller idx on tie
                bv = ov;
                bi = oi;
            }
        }
        if (col == 0) {
            const int row = row_base + (r & 3) + 8 * (r >> 2) + 4 * half_;
            pbest[(size_t)split * N_ROWS + row] = bv;
            pidx[(size_t)split * N_ROWS + row] = bi;
        }
    }
}

// ---------------------------------------------------------------------------
// Kernel 2: combine splits, gather quantize rows, write index-as-float.
// One thread per (row, float4-chunk): t in [0, N_ROWS*16).
// ---------------------------------------------------------------------------
__global__ void combine_kernel(const float* __restrict__ pbest,
                               const int* __restrict__ pidx,
                               const float* __restrict__ embed,
                               float* __restrict__ out) {
    const int t = blockIdx.x * blockDim.x + threadIdx.x;
    const int row = t >> 4;
    const int q = t & 15;
    if (row >= N_ROWS) return;

    float best = -INFINITY;
    int bi = 0;
#pragma unroll
    for (int s = 0; s < SPLITS; ++s) {
        float b = pbest[(size_t)s * N_ROWS + row];
        int i = pidx[(size_t)s * N_ROWS + row];
        if (b > best) {  // splits ascending in k; strict > keeps earliest
            best = b;
            bi = i;
        }
    }

    const float4* e4 = reinterpret_cast<const float4*>(embed);
    float4 v = e4[(size_t)bi * (DIM / 4) + q];
    reinterpret_cast<float4*>(out)[(size_t)row * (DIM / 4) + q] = v;
    if (q == 0) {
        out[(size_t)QUANT_ELEMS + row] = (float)bi;  // index as float
    }
}

// ---------------------------------------------------------------------------
extern "C" void kernel_launch(void* const* d_in, const int* in_sizes, int n_in,
                              void* d_out, int out_size, void* d_ws,
                              size_t ws_size, hipStream_t stream) {
    const float* x = (const float*)d_in[0];
    const float* embed = (const float*)d_in[1];
    float* out = (float*)d_out;

    // ws: sq 16KB | ehi 512KB | elo 512KB | pbest 512KB | pidx 512KB
    char* ws = (char*)d_ws;
    float* sq = (float*)ws;
    half8* ehi = (half8*)(ws + 16384);
    half8* elo = (half8*)(ws + 16384 + 524288);
    float* pbest = (float*)(ws + 16384 + 2 * 524288);
    int* pidx = (int*)(ws + 16384 + 2 * 524288 + SPLITS * N_ROWS * 4);

    prep_kernel<<<TILES_TOTAL, 256, 0, stream>>>(embed, sq, ehi, elo);

    dim3 grid(N_ROWS / 128, SPLITS);
    fused_dist_argmax32<<<grid, 256, 0, stream>>>(x, sq, ehi, elo, pbest,
                                                  pidx);

    const int combine_threads = N_ROWS * (DIM / 4);
    combine_kernel<<<(combine_threads + 255) / 256, 256, 0, stream>>>(
        pbest, pidx, embed, out);
}